// Round 5
// baseline (131.712 us; speedup 1.0000x reference)
//
#include <hip/hip_runtime.h>
#include <math.h>

#define NN_ 256      // nodes per graph
#define BB_ 64       // batch
#define FF_ 5        // features
#define NE_ 65536    // NN_*NN_

// workspace layout in floats (~3 MB used, L2/L3-resident)
// Pure ops (build_all): Op[r*256+c] = edge weight for edge (row=r,col=c).
// Stage math: y_c = 0.1 x_c + 0.45 dis_c sum_r Op[r,c] dis_r x_r,
// i.e. y = L x with L^T[r][c] = 0.1 d_rc + 0.45 dis_r dis_c Op[r][c] == F.
// Composition (ReLU only after stage 2):
//   o = L4 L3 relu(L2 L1 L0 x) = M_B relu(M_A x)
//   MTA := M_A^T = F0*F1*F2,  MTB := M_B^T = F3*F4   (row-major products)
// Chain consumes MT directly: y_c = sum_r MT[r*256+c] x_r (coalesced).
#define OFF_SLA 0        // pure w              (stages 1,3)
#define OFF_SL1 65536    // z0*w                (stage 0)
#define OFF_SL3 131072   // z1*w                (stage 2)
#define OFF_SL5 196608   // z2*w                (stage 4)
#define OFF_DIS 262144   // 256 floats
#define OFF_FA  327680   // F_A  = 0.1I + 0.45 D W D
#define OFF_FZ0 393216   // F_z0
#define OFF_FZ1 458752   // F_z1
#define OFF_FZ2 524288   // F_z2
#define OFF_T1  589824   // T1  = F_z0 * F_A
#define OFF_MTA 655360   // MTA = T1 * F_z1   (= M_A^T)
#define OFF_MTB 720896   // MTB = F_A * F_z2  (= M_B^T)

// ---------------------------------------------------------------------------
// K1: fused build (known-good). Block i = operator row i. One p-row gather
// serves BOTH the deg reduction (dis_i) and the four pure-operator writes.
// Block 0 lanes 0..2 emit the scalar tail (kld_loss, drop_rates).
// ---------------------------------------------------------------------------
__global__ __launch_bounds__(256) void build_all(
    const float* __restrict__ p, const float* __restrict__ u_rb,
    const float* __restrict__ a_uc, const float* __restrict__ b_uc,
    const float* __restrict__ u_pi, float* __restrict__ ws,
    float* __restrict__ out) {
  const int i = blockIdx.x, j = threadIdx.x;
  const int t = (i >= j) ? (i * (i + 1) / 2 + j) : (j * (j + 1) / 2 + i);
  const float w = p[t];

  __shared__ float sh[NN_];
  __shared__ float slg[3];
  __shared__ float skld[3];
  sh[j] = fabsf(w);

  if (j < 3) {
    const int l = j;
    const float au = fmaxf(a_uc[l], -10.0f);
    const float bu = fminf(fmaxf(b_uc[l], -10.0f), 50.0f);
    const float a = log1pf(expf(au));
    const float b = log1pf(expf(bu));
    const float up = fminf(fmaxf(u_pi[l], 1e-6f), 1.0f - 1e-6f);
    const float pi = powf(1.0f - powf(up, 1.0f / b), 1.0f / a);
    slg[l] = logf(pi) - log1pf(-pi);
    if (i == 0) {
      out[193 + l] = pi;  // drop_rates
      float x = b, dg = 0.0f;
      while (x < 6.0f) { dg -= 1.0f / x; x += 1.0f; }
      const float inv = 1.0f / x, inv2 = inv * inv;
      dg += logf(x) - 0.5f * inv
            - inv2 * (1.0f / 12.0f - inv2 * (1.0f / 120.0f - inv2 * (1.0f / 252.0f)));
      const float euler = 0.577215664901532f;
      skld[l] = (1.0f - 0.8f / a) * (-euler - dg - 1.0f / b)
                + logf(a * b + 1e-10f) - logf(0.8f) - (b - 1.0f) / b;
    }
  }
  __syncthreads();

  // deg_i = sum_j |W[i,j]| via LDS tree reduction over the row we just loaded
  for (int s = NN_ / 2; s > 0; s >>= 1) {
    if (j < s) sh[j] += sh[j + s];
    __syncthreads();
  }
  if (j == 0) {
    const float deg = sh[0];
    ws[OFF_DIS + i] = (deg > 0.0f) ? (1.0f / sqrtf(deg)) : 0.0f;
    if (i == 0) out[192] = skld[0] + skld[1] + skld[2];  // kld_loss
  }

  // pure (un-normalized) operators; coalesced u_rb reads and ws writes
  const float lg0 = slg[0];
  const float lg1 = slg[1];
  const float lg2 = slg[2];
  const int idx = i * NN_ + j;
  const float inv_temp = 1.0f / 0.6f;

  ws[OFF_SLA + idx] = w;

  float u, v;
  u = fminf(fmaxf(u_rb[0 * NE_ + idx], 1e-6f), 1.0f - 1e-6f);
  v = (lg0 + logf(u) - log1pf(-u)) * inv_temp;
  ws[OFF_SL1 + idx] = w / (1.0f + expf(-v));

  u = fminf(fmaxf(u_rb[1 * NE_ + idx], 1e-6f), 1.0f - 1e-6f);
  v = (lg1 + logf(u) - log1pf(-u)) * inv_temp;
  ws[OFF_SL3 + idx] = w / (1.0f + expf(-v));

  u = fminf(fmaxf(u_rb[2 * NE_ + idx], 1e-6f), 1.0f - 1e-6f);
  v = (lg2 + logf(u) - log1pf(-u)) * inv_temp;
  ws[OFF_SL5 + idx] = w / (1.0f + expf(-v));
}

// ---------------------------------------------------------------------------
// K2: materialize the normalized stage matrices F = 0.1I + 0.45 D Op D.
// Block i, lane j: all reads/writes coalesced.
// ---------------------------------------------------------------------------
__global__ __launch_bounds__(256) void norm_ops(float* __restrict__ ws) {
  const int i = blockIdx.x, j = threadIdx.x;
  const int idx = i * NN_ + j;
  const float di = ws[OFF_DIS + i];   // wave-uniform
  const float dj = ws[OFF_DIS + j];   // coalesced
  const float s = 0.45f * di * dj;
  const float d = (i == j) ? 0.1f : 0.0f;
  ws[OFF_FA  + idx] = d + s * ws[OFF_SLA + idx];
  ws[OFF_FZ0 + idx] = d + s * ws[OFF_SL1 + idx];
  ws[OFF_FZ1 + idx] = d + s * ws[OFF_SL3 + idx];
  ws[OFF_FZ2 + idx] = d + s * ws[OFF_SL5 + idx];
}

// ---------------------------------------------------------------------------
// K3: two independent 256^3 GEMMs, one output row per block (512 blocks ->
// 2 blocks/CU, 2 waves/SIMD). F-row staged in LDS (broadcast reads);
// G-column streamed coalesced from L2. 4 accumulators break the FMA chain.
//   bid < 256 : T1[r][j]  = sum_k FZ0[r][k] * FA[k][j]
//   bid >= 256: MTB[r][j] = sum_k FA[r][k]  * FZ2[k][j]
// ---------------------------------------------------------------------------
__global__ __launch_bounds__(256) void gemm_pair(float* __restrict__ ws) {
  const int bid = blockIdx.x, j = threadIdx.x;
  const int r = bid & 255;
  const bool g2 = bid >= 256;
  const float* __restrict__ F = ws + (g2 ? OFF_FA : OFF_FZ0) + r * NN_;
  const float* __restrict__ G = ws + (g2 ? OFF_FZ2 : OFF_FA) + j;
  float* __restrict__ D = ws + (g2 ? OFF_MTB : OFF_T1) + r * NN_ + j;

  __shared__ float Fr[NN_];
  Fr[j] = F[j];
  __syncthreads();

  float a0 = 0.f, a1 = 0.f, a2 = 0.f, a3 = 0.f;
#pragma unroll 4
  for (int k = 0; k < NN_; k += 4) {
    a0 += Fr[k + 0] * G[(k + 0) * NN_];
    a1 += Fr[k + 1] * G[(k + 1) * NN_];
    a2 += Fr[k + 2] * G[(k + 2) * NN_];
    a3 += Fr[k + 3] * G[(k + 3) * NN_];
  }
  *D = (a0 + a1) + (a2 + a3);
}

// ---------------------------------------------------------------------------
// K4: MTA[r][j] = sum_k T1[r][k] * FZ1[k][j]. 256 blocks x 512 threads
// (2-way k-split -> 8 waves/block, 2 waves/SIMD for latency hiding).
// ---------------------------------------------------------------------------
__global__ __launch_bounds__(512) void gemm_mta(float* __restrict__ ws) {
  const int r = blockIdx.x;
  const int tid = threadIdx.x;
  const int j = tid & 255, h = tid >> 8;  // h = k-half
  __shared__ float Tr[NN_];
  __shared__ float prt[2][NN_];
  if (tid < NN_) Tr[tid] = ws[OFF_T1 + r * NN_ + tid];
  __syncthreads();

  const float* __restrict__ G = ws + OFF_FZ1 + j;
  const int k0 = h * 128;
  float a0 = 0.f, a1 = 0.f, a2 = 0.f, a3 = 0.f;
#pragma unroll 4
  for (int k = k0; k < k0 + 128; k += 4) {
    a0 += Tr[k + 0] * G[(k + 0) * NN_];
    a1 += Tr[k + 1] * G[(k + 1) * NN_];
    a2 += Tr[k + 2] * G[(k + 2) * NN_];
    a3 += Tr[k + 3] * G[(k + 3) * NN_];
  }
  prt[h][j] = (a0 + a1) + (a2 + a3);
  __syncthreads();
  if (tid < NN_)
    ws[OFF_MTA + r * NN_ + tid] = prt[0][tid] + prt[1][tid];
}

// ---------------------------------------------------------------------------
// K5: per-batch chain, now only TWO stages: Y = relu(MTA^T-apply(x)),
// o = MTB^T-apply(Y). 64 blocks x 1024 threads; 8-way k-split, 2 j-cols
// per thread (round-4 structure); no dis / 0.1x terms (folded into MT).
// Head unchanged. LDS: 16 + 64 KB.
// ---------------------------------------------------------------------------
__global__ __launch_bounds__(1024) void batch_chain(
    const float* __restrict__ x0g, const float* __restrict__ ws,
    const float* __restrict__ lin_w, const float* __restrict__ lin_b,
    const float* __restrict__ fc_w, const float* __restrict__ fc_b,
    float* __restrict__ out) {
  const int b = blockIdx.x, tid = threadIdx.x;
  __shared__ float xbuf[2][NN_ * 8];   // 16 KB ping-pong
  __shared__ float part[8 * NN_ * 8];  // 64 KB partials (reused by head)
  float* Xc = xbuf[0];
  float* Xn = xbuf[1];

  // stage input x[b] (layout [b*256+i][5]) into padded LDS rows [i][8]
  for (int idx = tid; idx < NN_ * FF_; idx += 1024) {
    const int i = idx / 5, f = idx - 5 * i;
    Xc[i * 8 + f] = x0g[b * (NN_ * FF_) + idx];
  }
  __syncthreads();

  const int q = tid >> 7;       // k-eighth 0..7
  const int j0 = tid & 127;     // first output node (second = j0+128)
  const int k0 = q * 32;

#pragma unroll
  for (int l = 0; l < 2; ++l) {
    const float* __restrict__ Op = ws + (l == 0 ? OFF_MTA : OFF_MTB) + j0;
    float4 p03 = {0.f, 0.f, 0.f, 0.f};
    float4 r03 = {0.f, 0.f, 0.f, 0.f};
    float p4 = 0.f, r4 = 0.f;
#pragma unroll 8
    for (int k = k0; k < k0 + 32; ++k) {
      const float w0 = Op[k * NN_];                     // coalesced (L2)
      const float w1 = Op[k * NN_ + 128];               // coalesced (L2)
      const float4 xv = *(const float4*)(Xc + k * 8);   // LDS broadcast
      const float x4 = Xc[k * 8 + 4];                   // LDS broadcast
      p03.x += w0 * xv.x; p03.y += w0 * xv.y;
      p03.z += w0 * xv.z; p03.w += w0 * xv.w; p4 += w0 * x4;
      r03.x += w1 * xv.x; r03.y += w1 * xv.y;
      r03.z += w1 * xv.z; r03.w += w1 * xv.w; r4 += w1 * x4;
    }
    float* const pp0 = part + (q * NN_ + j0) * 8;
    float* const pp1 = part + (q * NN_ + j0 + 128) * 8;
    *(float4*)pp0 = p03; pp0[4] = p4;
    *(float4*)pp1 = r03; pp1[4] = r4;
    __syncthreads();
    // combine 8 k-eighths: 2048 padded entries (pads garbage, never read)
    for (int idx = tid; idx < 2048; idx += 1024) {
      float sum = part[idx];
#pragma unroll
      for (int qq = 1; qq < 8; ++qq) sum += part[qq * 2048 + idx];
      Xn[idx] = (l == 0) ? fmaxf(sum, 0.f) : sum;
    }
    __syncthreads();
    float* tp = Xc; Xc = Xn; Xn = tp;
  }

  // head: Xc holds o (256 x 5, padded 8). relu(o@lin_w+lin_b) -> pool -> fc.
  const int k = tid & 127, seg = tid >> 7;  // 8 segs x 32 rows
  const float lw0 = lin_w[0 * 128 + k];
  const float lw1 = lin_w[1 * 128 + k];
  const float lw2 = lin_w[2 * 128 + k];
  const float lw3 = lin_w[3 * 128 + k];
  const float lw4 = lin_w[4 * 128 + k];
  const float lb = lin_b[k];
  float acc = 0.f;
  const int r0 = seg * 32;
#pragma unroll 4
  for (int jj = r0; jj < r0 + 32; ++jj) {
    const float4 ov = *(const float4*)(Xc + jj * 8);  // LDS broadcast
    const float o4 = Xc[jj * 8 + 4];
    const float vv = lb + lw0 * ov.x + lw1 * ov.y + lw2 * ov.z +
                     lw3 * ov.w + lw4 * o4;
    acc += fmaxf(vv, 0.f);
  }
  part[seg * 128 + k] = acc;
  __syncthreads();
  if (tid < 128) {
    float s = 0.f;
#pragma unroll
    for (int s8 = 0; s8 < 8; ++s8) s += part[s8 * 128 + tid];
    part[tid] = s;  // pooled[k]
  }
  __syncthreads();
  if (tid < 3) {
    float s = fc_b[tid];
    for (int kk = 0; kk < 128; ++kk) s += part[kk] * fc_w[kk * 3 + tid];
    out[b * 3 + tid] = s;
  }
}

// ---------------------------------------------------------------------------
extern "C" void kernel_launch(void* const* d_in, const int* in_sizes, int n_in,
                              void* d_out, int out_size, void* d_ws,
                              size_t ws_size, hipStream_t stream) {
  const float* x      = (const float*)d_in[0];
  const float* p      = (const float*)d_in[1];
  const float* a_uc   = (const float*)d_in[2];
  const float* b_uc   = (const float*)d_in[3];
  const float* u_pi   = (const float*)d_in[4];
  const float* u_rb   = (const float*)d_in[5];
  const float* lin_w  = (const float*)d_in[6];
  const float* lin_b  = (const float*)d_in[7];
  const float* fc_w   = (const float*)d_in[8];
  const float* fc_b   = (const float*)d_in[9];
  // d_in[10] edge_index, d_in[11] batch: fully deterministic, never read.
  float* out = (float*)d_out;
  float* ws  = (float*)d_ws;

  build_all<<<256, 256, 0, stream>>>(p, u_rb, a_uc, b_uc, u_pi, ws, out);
  norm_ops<<<256, 256, 0, stream>>>(ws);
  gemm_pair<<<512, 256, 0, stream>>>(ws);
  gemm_mta<<<256, 512, 0, stream>>>(ws);
  batch_chain<<<64, 1024, 0, stream>>>(x, ws, lin_w, lin_b, fc_w, fc_b, out);
}

// Round 6
// 130.362 us; speedup vs baseline: 1.0104x; 1.0104x over previous
//
#include <hip/hip_runtime.h>
#include <math.h>

#define NN_ 256      // nodes per graph
#define BB_ 64       // batch
#define FF_ 5        // features
#define NE_ 65536    // NN_*NN_

// workspace layout in floats (~1.8 MB used, L2-resident)
// build_all writes ROW-SCALED pure ops: SLxd[i*256+j] = (z*)w[i][j] * dis_i.
// Normalized stage matrix: F[i][j] = 0.1*d_ij + 0.45 * SLxd[i][j] * dis_j
// (dis_j applied on the fly in the GEMMs; dis_i folded at build).
// Stage apply (verified rounds 1-5): y_j = sum_i F[i*256+j] * x_i.
// Composition (ReLU only after stage 2):
//   o = M_B relu(M_A x);  MTA = F_z0*F_A*F_z1, MTB = F_A*F_z2 (row-major)
//   computed as T2 = F_A*F_z1, MTB = F_A*F_z2 (independent), MTA = F_z0*T2.
// Chain consumes MTA/MTB directly: y_j = sum_k MT[k*256+j] x_k.
#define OFF_SLA 0        // w * dis_i           (stages 1,3)
#define OFF_SL1 65536    // z0*w * dis_i        (stage 0)
#define OFF_SL3 131072   // z1*w * dis_i        (stage 2)
#define OFF_SL5 196608   // z2*w * dis_i        (stage 4)
#define OFF_DIS 262144   // 256 floats
#define OFF_T2  327680   // T2  = F_A * F_z1
#define OFF_MTA 393216   // MTA = F_z0 * T2   (= M_A^T)
#define OFF_MTB 458752   // MTB = F_A * F_z2  (= M_B^T)

// ---------------------------------------------------------------------------
// K1: fused build. Block i = operator row i. One p-row gather serves the deg
// reduction (dis_i, broadcast to all lanes) and the four ROW-SCALED operator
// writes. Block 0 lanes 0..2 emit the scalar tail (kld_loss, drop_rates).
// ---------------------------------------------------------------------------
__global__ __launch_bounds__(256) void build_all(
    const float* __restrict__ p, const float* __restrict__ u_rb,
    const float* __restrict__ a_uc, const float* __restrict__ b_uc,
    const float* __restrict__ u_pi, float* __restrict__ ws,
    float* __restrict__ out) {
  const int i = blockIdx.x, j = threadIdx.x;
  const int t = (i >= j) ? (i * (i + 1) / 2 + j) : (j * (j + 1) / 2 + i);
  const float w = p[t];

  __shared__ float sh[NN_];
  __shared__ float slg[3];
  __shared__ float skld[3];
  sh[j] = fabsf(w);

  if (j < 3) {
    const int l = j;
    const float au = fmaxf(a_uc[l], -10.0f);
    const float bu = fminf(fmaxf(b_uc[l], -10.0f), 50.0f);
    const float a = log1pf(expf(au));
    const float b = log1pf(expf(bu));
    const float up = fminf(fmaxf(u_pi[l], 1e-6f), 1.0f - 1e-6f);
    const float pi = powf(1.0f - powf(up, 1.0f / b), 1.0f / a);
    slg[l] = logf(pi) - log1pf(-pi);
    if (i == 0) {
      out[193 + l] = pi;  // drop_rates
      float x = b, dg = 0.0f;
      while (x < 6.0f) { dg -= 1.0f / x; x += 1.0f; }
      const float inv = 1.0f / x, inv2 = inv * inv;
      dg += logf(x) - 0.5f * inv
            - inv2 * (1.0f / 12.0f - inv2 * (1.0f / 120.0f - inv2 * (1.0f / 252.0f)));
      const float euler = 0.577215664901532f;
      skld[l] = (1.0f - 0.8f / a) * (-euler - dg - 1.0f / b)
                + logf(a * b + 1e-10f) - logf(0.8f) - (b - 1.0f) / b;
    }
  }
  __syncthreads();

  // deg_i = sum_j |W[i,j]| via LDS tree reduction over the row we just loaded
  for (int s = NN_ / 2; s > 0; s >>= 1) {
    if (j < s) sh[j] += sh[j + s];
    __syncthreads();
  }
  const float deg = sh[0];  // broadcast (post final barrier)
  const float disi = (deg > 0.0f) ? (1.0f / sqrtf(deg)) : 0.0f;
  if (j == 0) {
    ws[OFF_DIS + i] = disi;
    if (i == 0) out[192] = skld[0] + skld[1] + skld[2];  // kld_loss
  }

  // row-scaled operators; coalesced u_rb reads and ws writes
  const float lg0 = slg[0];
  const float lg1 = slg[1];
  const float lg2 = slg[2];
  const int idx = i * NN_ + j;
  const float inv_temp = 1.0f / 0.6f;
  const float wd = w * disi;

  ws[OFF_SLA + idx] = wd;

  float u, v;
  u = fminf(fmaxf(u_rb[0 * NE_ + idx], 1e-6f), 1.0f - 1e-6f);
  v = (lg0 + logf(u) - log1pf(-u)) * inv_temp;
  ws[OFF_SL1 + idx] = wd / (1.0f + expf(-v));

  u = fminf(fmaxf(u_rb[1 * NE_ + idx], 1e-6f), 1.0f - 1e-6f);
  v = (lg1 + logf(u) - log1pf(-u)) * inv_temp;
  ws[OFF_SL3 + idx] = wd / (1.0f + expf(-v));

  u = fminf(fmaxf(u_rb[2 * NE_ + idx], 1e-6f), 1.0f - 1e-6f);
  v = (lg2 + logf(u) - log1pf(-u)) * inv_temp;
  ws[OFF_SL5 + idx] = wd / (1.0f + expf(-v));
}

// ---------------------------------------------------------------------------
// K2: round-1 GEMMs, both reading F_A rows (independent):
//   bid < 256 : T2[r][j]  = sum_k F_A[r][k] * F_z1[k][j]
//   bid >= 256: MTB[r][j] = sum_k F_A[r][k] * F_z2[k][j]
// 1024 threads: j = tid&255, 4-way k-split (64 k, 4 accumulators -> 16
// loads in flight). 512 blocks -> 2 blocks/CU -> 8 waves/SIMD.
// Normalization on the fly: staged row gets 0.45*dis_k + diag; streamed
// operand gets per-lane-constant 0.45*dis_j + diag-select per iter.
// ---------------------------------------------------------------------------
__global__ __launch_bounds__(1024) void gemm_round1(float* __restrict__ ws) {
  const int bid = blockIdx.x;
  const int r = bid & 255;
  const bool g2 = bid >= 256;
  const int tid = threadIdx.x;
  const int j = tid & 255, kq = tid >> 8;

  __shared__ float Fr[NN_];
  __shared__ float sdis[NN_];
  __shared__ float part[4][NN_];

  if (tid < NN_) sdis[tid] = ws[OFF_DIS + tid];
  __syncthreads();
  if (tid < NN_) {
    float v = 0.45f * ws[OFF_SLA + r * NN_ + tid] * sdis[tid];
    if (tid == r) v += 0.1f;
    Fr[tid] = v;  // F_A[r][k]
  }
  __syncthreads();

  const float cj = 0.45f * sdis[j];      // per-lane constant
  const float* __restrict__ Gp = ws + (g2 ? OFF_SL5 : OFF_SL3) + j;
  const int k0 = kq * 64;
  float a0 = 0.f, a1 = 0.f, a2 = 0.f, a3 = 0.f;
#pragma unroll 4
  for (int k = k0; k < k0 + 64; k += 4) {
    float g0 = cj * Gp[(k + 0) * NN_]; if (k + 0 == j) g0 += 0.1f;
    float g1 = cj * Gp[(k + 1) * NN_]; if (k + 1 == j) g1 += 0.1f;
    float g2v = cj * Gp[(k + 2) * NN_]; if (k + 2 == j) g2v += 0.1f;
    float g3 = cj * Gp[(k + 3) * NN_]; if (k + 3 == j) g3 += 0.1f;
    a0 += Fr[k + 0] * g0;
    a1 += Fr[k + 1] * g1;
    a2 += Fr[k + 2] * g2v;
    a3 += Fr[k + 3] * g3;
  }
  part[kq][j] = (a0 + a1) + (a2 + a3);
  __syncthreads();
  if (tid < NN_)
    ws[(g2 ? OFF_MTB : OFF_T2) + r * NN_ + tid] =
        (part[0][tid] + part[1][tid]) + (part[2][tid] + part[3][tid]);
}

// ---------------------------------------------------------------------------
// K3: MTA[r][j] = sum_k F_z0[r][k] * T2[k][j]. Same structure; streamed T2
// is already composed (no normalization). 256 blocks -> 1 block/CU.
// ---------------------------------------------------------------------------
__global__ __launch_bounds__(1024) void gemm_round2(float* __restrict__ ws) {
  const int r = blockIdx.x;
  const int tid = threadIdx.x;
  const int j = tid & 255, kq = tid >> 8;

  __shared__ float Fr[NN_];
  __shared__ float part[4][NN_];

  if (tid < NN_) {
    const float dk = ws[OFF_DIS + tid];
    float v = 0.45f * ws[OFF_SL1 + r * NN_ + tid] * dk;
    if (tid == r) v += 0.1f;
    Fr[tid] = v;  // F_z0[r][k]
  }
  __syncthreads();

  const float* __restrict__ Gp = ws + OFF_T2 + j;
  const int k0 = kq * 64;
  float a0 = 0.f, a1 = 0.f, a2 = 0.f, a3 = 0.f;
#pragma unroll 4
  for (int k = k0; k < k0 + 64; k += 4) {
    a0 += Fr[k + 0] * Gp[(k + 0) * NN_];
    a1 += Fr[k + 1] * Gp[(k + 1) * NN_];
    a2 += Fr[k + 2] * Gp[(k + 2) * NN_];
    a3 += Fr[k + 3] * Gp[(k + 3) * NN_];
  }
  part[kq][j] = (a0 + a1) + (a2 + a3);
  __syncthreads();
  if (tid < NN_)
    ws[OFF_MTA + r * NN_ + tid] =
        (part[0][tid] + part[1][tid]) + (part[2][tid] + part[3][tid]);
}

// ---------------------------------------------------------------------------
// K4: per-batch chain, TWO stages (verified round-5 structure):
// Y = relu(MTA-apply(x)), o = MTB-apply(Y). 64 blocks x 1024 threads;
// 8-way k-split, 2 j-cols per thread. Head unchanged.
// ---------------------------------------------------------------------------
__global__ __launch_bounds__(1024) void batch_chain(
    const float* __restrict__ x0g, const float* __restrict__ ws,
    const float* __restrict__ lin_w, const float* __restrict__ lin_b,
    const float* __restrict__ fc_w, const float* __restrict__ fc_b,
    float* __restrict__ out) {
  const int b = blockIdx.x, tid = threadIdx.x;
  __shared__ float xbuf[2][NN_ * 8];   // 16 KB ping-pong
  __shared__ float part[8 * NN_ * 8];  // 64 KB partials (reused by head)
  float* Xc = xbuf[0];
  float* Xn = xbuf[1];

  // stage input x[b] (layout [b*256+i][5]) into padded LDS rows [i][8]
  for (int idx = tid; idx < NN_ * FF_; idx += 1024) {
    const int i = idx / 5, f = idx - 5 * i;
    Xc[i * 8 + f] = x0g[b * (NN_ * FF_) + idx];
  }
  __syncthreads();

  const int q = tid >> 7;       // k-eighth 0..7
  const int j0 = tid & 127;     // first output node (second = j0+128)
  const int k0 = q * 32;

#pragma unroll
  for (int l = 0; l < 2; ++l) {
    const float* __restrict__ Op = ws + (l == 0 ? OFF_MTA : OFF_MTB) + j0;
    float4 p03 = {0.f, 0.f, 0.f, 0.f};
    float4 r03 = {0.f, 0.f, 0.f, 0.f};
    float p4 = 0.f, r4 = 0.f;
#pragma unroll 8
    for (int k = k0; k < k0 + 32; ++k) {
      const float w0 = Op[k * NN_];                     // coalesced (L2)
      const float w1 = Op[k * NN_ + 128];               // coalesced (L2)
      const float4 xv = *(const float4*)(Xc + k * 8);   // LDS broadcast
      const float x4 = Xc[k * 8 + 4];                   // LDS broadcast
      p03.x += w0 * xv.x; p03.y += w0 * xv.y;
      p03.z += w0 * xv.z; p03.w += w0 * xv.w; p4 += w0 * x4;
      r03.x += w1 * xv.x; r03.y += w1 * xv.y;
      r03.z += w1 * xv.z; r03.w += w1 * xv.w; r4 += w1 * x4;
    }
    float* const pp0 = part + (q * NN_ + j0) * 8;
    float* const pp1 = part + (q * NN_ + j0 + 128) * 8;
    *(float4*)pp0 = p03; pp0[4] = p4;
    *(float4*)pp1 = r03; pp1[4] = r4;
    __syncthreads();
    // combine 8 k-eighths: 2048 padded entries (pads garbage, never read)
    for (int idx = tid; idx < 2048; idx += 1024) {
      float sum = part[idx];
#pragma unroll
      for (int qq = 1; qq < 8; ++qq) sum += part[qq * 2048 + idx];
      Xn[idx] = (l == 0) ? fmaxf(sum, 0.f) : sum;
    }
    __syncthreads();
    float* tp = Xc; Xc = Xn; Xn = tp;
  }

  // head: Xc holds o (256 x 5, padded 8). relu(o@lin_w+lin_b) -> pool -> fc.
  const int k = tid & 127, seg = tid >> 7;  // 8 segs x 32 rows
  const float lw0 = lin_w[0 * 128 + k];
  const float lw1 = lin_w[1 * 128 + k];
  const float lw2 = lin_w[2 * 128 + k];
  const float lw3 = lin_w[3 * 128 + k];
  const float lw4 = lin_w[4 * 128 + k];
  const float lb = lin_b[k];
  float acc = 0.f;
  const int r0 = seg * 32;
#pragma unroll 4
  for (int jj = r0; jj < r0 + 32; ++jj) {
    const float4 ov = *(const float4*)(Xc + jj * 8);  // LDS broadcast
    const float o4 = Xc[jj * 8 + 4];
    const float vv = lb + lw0 * ov.x + lw1 * ov.y + lw2 * ov.z +
                     lw3 * ov.w + lw4 * o4;
    acc += fmaxf(vv, 0.f);
  }
  part[seg * 128 + k] = acc;
  __syncthreads();
  if (tid < 128) {
    float s = 0.f;
#pragma unroll
    for (int s8 = 0; s8 < 8; ++s8) s += part[s8 * 128 + tid];
    part[tid] = s;  // pooled[k]
  }
  __syncthreads();
  if (tid < 3) {
    float s = fc_b[tid];
    for (int kk = 0; kk < 128; ++kk) s += part[kk] * fc_w[kk * 3 + tid];
    out[b * 3 + tid] = s;
  }
}

// ---------------------------------------------------------------------------
extern "C" void kernel_launch(void* const* d_in, const int* in_sizes, int n_in,
                              void* d_out, int out_size, void* d_ws,
                              size_t ws_size, hipStream_t stream) {
  const float* x      = (const float*)d_in[0];
  const float* p      = (const float*)d_in[1];
  const float* a_uc   = (const float*)d_in[2];
  const float* b_uc   = (const float*)d_in[3];
  const float* u_pi   = (const float*)d_in[4];
  const float* u_rb   = (const float*)d_in[5];
  const float* lin_w  = (const float*)d_in[6];
  const float* lin_b  = (const float*)d_in[7];
  const float* fc_w   = (const float*)d_in[8];
  const float* fc_b   = (const float*)d_in[9];
  // d_in[10] edge_index, d_in[11] batch: fully deterministic, never read.
  float* out = (float*)d_out;
  float* ws  = (float*)d_ws;

  build_all<<<256, 256, 0, stream>>>(p, u_rb, a_uc, b_uc, u_pi, ws, out);
  gemm_round1<<<512, 1024, 0, stream>>>(ws);
  gemm_round2<<<256, 1024, 0, stream>>>(ws);
  batch_chain<<<64, 1024, 0, stream>>>(x, ws, lin_w, lin_b, fc_w, fc_b, out);
}